// Round 10
// baseline (61.699 us; speedup 1.0000x reference)
//
#include <hip/hip_runtime.h>
#include <hip/hip_bf16.h>
#include <stdint.h>

#define HEIGHT 32
#define WIDTH  8192
#define KDIM   256
#define NDIM   512
#define NSLICES 65536                 // B * S = 64 * 1024
#define BM     32                     // slices per tile
#define TTILES 4                      // tiles per block
#define NBLOCKS (NSLICES / (BM * TTILES))   // 512

typedef float f32x4  __attribute__((ext_vector_type(4)));
typedef float f32x16 __attribute__((ext_vector_type(16)));
typedef short bf16x8 __attribute__((ext_vector_type(8)));

__device__ __forceinline__ ushort f2bf(float x) {
  union { float f; uint32_t u; } un; un.f = x;
  uint32_t u = un.u;
  u += 0x7FFFu + ((u >> 16) & 1u);   // round-to-nearest-even
  return (ushort)(u >> 16);
}

__device__ __forceinline__ void load_row8(float* r, const float* p) {
  f32x4 lo = *reinterpret_cast<const f32x4*>(p);
  f32x4 hi = *reinterpret_cast<const f32x4*>(p + 4);
#pragma unroll
  for (int w = 0; w < 4; ++w) { r[w] = lo[w]; r[4 + w] = hi[w]; }
}

// ---- wt2: B-fragment-tiled layout (proven R7/R8) ----
// wt2[((nb*16 + k0)*64 + lane)*8 + e] = bf16(lin_w[k][n]),
//   n = nb*32 + (lane&31), k = k0*16 + (lane>>5)*8 + e.
__global__ __launch_bounds__(256) void prep_wt2_kernel(const float* __restrict__ lin_w,
                                                       ushort* __restrict__ wt2) {
  const int idx = blockIdx.x * 256 + threadIdx.x;   // 0..16383
  const int ln  = idx & 63;
  const int k0  = (idx >> 6) & 15;
  const int nb  = idx >> 10;
  const int n   = nb * 32 + (ln & 31);
  const int kb  = k0 * 16 + (ln >> 5) * 8;
  bf16x8 p;
#pragma unroll
  for (int e = 0; e < 8; ++e) p[e] = (short)f2bf(lin_w[(size_t)(kb + e) * NDIM + n]);
  *reinterpret_cast<bf16x8*>(wt2 + (size_t)idx * 8) = p;
}

// ---------------- wave-specialized fused kernel ----------------
// 512 threads: waves 0-3 conv role, waves 4-7 gemm role. T=4 tiles of 32 slices.
// Stage s: conv -> A[s&1] (tile s) while gemm consumes A[(s-1)&1] (tile s-1).
__global__ __launch_bounds__(512) void fused_kernel(
    const float* __restrict__ images, const float* __restrict__ conv_w,
    const float* __restrict__ conv_b, const ushort* __restrict__ wt2,
    const float* __restrict__ lin_b, float* __restrict__ out) {
  __shared__ ushort A[2][16 * 64 * 8];   // 2 x 16 KB, A-fragment order

  const int tid = threadIdx.x;
  const int grp = tid >> 8;              // 0 = conv waves, 1 = gemm waves
  const int blk = blockIdx.x;            // 0..511

  float cw[9];
#pragma unroll
  for (int i = 0; i < 9; ++i) cw[i] = conv_w[i];
  const float cb = conv_b[0];

  // conv-role indices
  const int c_sl = tid & 31;             // slice within tile
  const int c_q  = (tid >> 5) & 7;       // 0..7: output rows q*4..q*4+3
  const int c_h0 = c_q * 4;

  // gemm-role indices
  const int gt   = tid & 255;
  const int lane = gt & 63;
  const int wv   = gt >> 6;              // 0..3
  const int la   = lane & 31;
  const int lb   = lane >> 5;

#pragma unroll
  for (int s = 0; s <= TTILES; ++s) {
    if (grp == 0) {
      if (s < TTILES) {
        // ---------- conv role: tile (blk*T+s) -> A[s&1] ----------
        const int t   = blk * TTILES + s;
        const int gsl = t * BM + c_sl;         // global slice
        const int b   = gsl >> 10;             // batch (1024 slices/batch)
        const int slb = gsl & 1023;
        const float* base = images + (size_t)b * (HEIGHT * WIDTH) + (size_t)slb * 8;
        ushort* Ab = A[s & 1];

        float r[6][8];
#pragma unroll
        for (int i = 0; i < 6; ++i) {
          const int h = c_h0 - 1 + i;
          if (h >= 0 && h < HEIGHT) load_row8(r[i], base + (size_t)h * WIDTH);
          else {
#pragma unroll
            for (int w = 0; w < 8; ++w) r[i][w] = 0.f;
          }
        }

#pragma unroll
        for (int oh = 0; oh < 4; ++oh) {
          const int h = c_h0 + oh;
          float y[8];
#pragma unroll
          for (int w = 0; w < 8; ++w) y[w] = cb;
#pragma unroll
          for (int dh = 0; dh < 3; ++dh) {
#pragma unroll
            for (int dw = 0; dw < 3; ++dw) {
              const float c = cw[dh * 3 + dw];
#pragma unroll
              for (int w = 0; w < 8; ++w) {
                const int iw = w + dw - 1;     // per-slice zero padding in w
                if (iw >= 0 && iw < 8) y[w] = fmaf(r[oh + dh][iw], c, y[w]);
              }
            }
          }
          bf16x8 pack;
#pragma unroll
          for (int w = 0; w < 8; ++w) pack[w] = (short)f2bf(fmaxf(y[w], 0.f));
          const int k0 = h >> 1;
          const int ln = ((h & 1) << 5) | c_sl;
          *reinterpret_cast<bf16x8*>(Ab + ((size_t)k0 * 64 + ln) * 8) = pack;
        }
      }
    } else {
      if (s >= 1) {
        // ---------- gemm role: tile (blk*T+s-1) from A[(s-1)&1] ----------
        const int t = blk * TTILES + s - 1;
        const ushort* abase = A[(s - 1) & 1] + (size_t)lane * 8;
        const size_t row0 = (size_t)t * BM;

#pragma unroll
        for (int pass = 0; pass < 2; ++pass) {
          const int nfb = wv * 4 + pass * 2;   // first of 2 n-frags
          const ushort* bb = wt2 + ((size_t)nfb * 16) * 512 + (size_t)lane * 8;

          f32x16 acc[2];
#pragma unroll
          for (int nf = 0; nf < 2; ++nf)
#pragma unroll
            for (int i = 0; i < 16; ++i) acc[nf][i] = 0.f;

#pragma unroll
          for (int k0 = 0; k0 < 16; ++k0) {
            const bf16x8 af  = *reinterpret_cast<const bf16x8*>(abase + (size_t)k0 * 512);
            const bf16x8 bf0 = *reinterpret_cast<const bf16x8*>(bb + (size_t)k0 * 512);
            const bf16x8 bf1 = *reinterpret_cast<const bf16x8*>(bb + (size_t)(16 + k0) * 512);
            __builtin_amdgcn_s_setprio(1);
            acc[0] = __builtin_amdgcn_mfma_f32_32x32x16_bf16(af, bf0, acc[0], 0, 0, 0);
            acc[1] = __builtin_amdgcn_mfma_f32_32x32x16_bf16(af, bf1, acc[1], 0, 0, 0);
            __builtin_amdgcn_s_setprio(0);
          }

          // store this pass's 32x64 block (keeps the write stream continuous)
#pragma unroll
          for (int nf = 0; nf < 2; ++nf) {
            const int col = (nfb + nf) * 32 + la;
            const float bias = lin_b[col];
#pragma unroll
            for (int reg = 0; reg < 16; ++reg) {
              const int rr = (reg & 3) + 8 * (reg >> 2) + 4 * lb;
              out[(row0 + rr) * NDIM + col] = acc[nf][reg] + bias;
            }
          }
        }
      }
    }
    __syncthreads();
  }
}

extern "C" void kernel_launch(void* const* d_in, const int* in_sizes, int n_in,
                              void* d_out, int out_size, void* d_ws, size_t ws_size,
                              hipStream_t stream) {
  const float* images = (const float*)d_in[0];
  const float* conv_w = (const float*)d_in[1];
  const float* conv_b = (const float*)d_in[2];
  const float* lin_w  = (const float*)d_in[3];
  const float* lin_b  = (const float*)d_in[4];
  float* out = (float*)d_out;
  ushort* wt2 = (ushort*)d_ws;      // 256 KB

  hipLaunchKernelGGL(prep_wt2_kernel, dim3(64), dim3(256), 0, stream, lin_w, wt2);
  hipLaunchKernelGGL(fused_kernel, dim3(NBLOCKS), dim3(512), 0, stream,
                     images, conv_w, conv_b, wt2, lin_b, out);
}